// Round 10
// baseline (144.974 us; speedup 1.0000x reference)
//
#include <hip/hip_runtime.h>

#define SK 8192
#define SQ 8192
#define DD 128
#define ZSPLIT 8

typedef __attribute__((ext_vector_type(8))) short short8;
typedef __attribute__((ext_vector_type(4))) float f32x4;
typedef __attribute__((ext_vector_type(4))) unsigned uint4v;
typedef unsigned short ushort_t;

// round-to-nearest-even f32 -> bf16
__device__ __forceinline__ unsigned short f2bf(float x){
  unsigned int u = __float_as_uint(x);
  u += 0x7FFFu + ((u >> 16) & 1u);
  return (unsigned short)(u >> 16);
}

// async global->LDS DMA, 16B/lane. LDS dest = uniform base + lane*16.
__device__ __forceinline__ void gld16(const void* g, void* l){
  __builtin_amdgcn_global_load_lds(
      (const __attribute__((address_space(1))) unsigned int*)g,
      (__attribute__((address_space(3))) unsigned int*)l, 16, 0, 0);
}

// ---------------------------------------------------------------------------
// STREAM LAYOUTS (fragment-record form; all reads are coalesced 1KB records)
// K/Q stream: per 64-row tile, 16 records of 1KB; rec = rg*4 + kk
//   (rg = row-group of 16, kk = 32-col depth group). Lane l, bytes j*2:
//   element M[tile*64 + rg*16 + (l&15)][kk*32 + (l>>4)*8 + j].
// V stream: per 64-q tile, 16 records; rec = qc*8 + dvb. Lane l:
//   element V^T[dvb*16 + (l&15)][qc*32 + (l>>4)*8 + j]  (V^T pre-scaled 1/Z)
// ---------------------------------------------------------------------------

// prep_kq: cast K (pre-scaled by log2(e)/sqrt(128)) and Q to bf16 streams.
__global__ __launch_bounds__(256) void prep_kq(const float* __restrict__ Kp,
                                               const float* __restrict__ Qp,
                                               ushort_t* __restrict__ kst,
                                               ushort_t* __restrict__ qst){
  int g = blockIdx.x*256 + threadIdx.x;
  int arr = g >> 17;
  int s   = g & 131071;
  int row = s >> 4;
  int c16 = s & 15;            // 8-elem slot: d = c16*8..c16*8+7
  const float* src = (arr ? Qp : Kp) + row*DD + c16*8;
  const float scale = arr ? 1.0f : 0.12751743f;   // log2(e)/sqrt(128)
  float4 f0 = ((const float4*)src)[0];
  float4 f1 = ((const float4*)src)[1];
  unsigned int wv[4];
  wv[0] = (unsigned)f2bf(f0.x*scale) | ((unsigned)f2bf(f0.y*scale) << 16);
  wv[1] = (unsigned)f2bf(f0.z*scale) | ((unsigned)f2bf(f0.w*scale) << 16);
  wv[2] = (unsigned)f2bf(f1.x*scale) | ((unsigned)f2bf(f1.y*scale) << 16);
  wv[3] = (unsigned)f2bf(f1.z*scale) | ((unsigned)f2bf(f1.w*scale) << 16);
  ushort_t* base = arr ? qst : kst;
  int tile = row >> 6, rg = (row >> 4) & 3, r15 = row & 15;
  int kk = c16 >> 2, g4 = c16 & 3;
  char* dst = (char*)base + (size_t)tile*16384 + (rg*4 + kk)*1024 + (g4*16 + r15)*16;
  ((uint4*)dst)[0] = make_uint4(wv[0],wv[1],wv[2],wv[3]);
}

// ---------------------------------------------------------------------------
// kz: per-column stats. K staged (linear 16KB copy) + dbuf; records read
// conflict-free from LDS; Q-frags coalesced from stream into regs.
// ---------------------------------------------------------------------------
__global__ __launch_bounds__(256, 4) void kz(const ushort_t* __restrict__ kst,
                                             const ushort_t* __restrict__ qst,
                                             float* __restrict__ zpart){
  __shared__ __align__(16) char smem[33792];   // K dbuf 2x16KB | zred 1KB
  int wg = blockIdx.x;            // 1024
  int qs   = wg >> 3;             // 0..127 (64-q stripe)
  int kspl = wg & 7;
  int t = threadIdx.x, lane = t & 63, w = t >> 6;   // w in 0..3
  int r15 = lane & 15, g4 = lane >> 4;

  { const char* kg = (const char*)kst + (size_t)(kspl*16)*16384;
    #pragma unroll
    for (int i=0;i<4;i++)
      gld16(kg + (t + i*256)*16, smem + (t + i*256)*16);
  }
  short8 qf[4][4];
  { const char* qg = (const char*)qst + (size_t)qs*16384;
    #pragma unroll
    for (int qg_=0; qg_<4; ++qg_)
      #pragma unroll
      for (int kk=0; kk<4; ++kk)
        qf[qg_][kk] = *(const short8*)(qg + ((qg_*4+kk)<<10) + lane*16);
  }
  __syncthreads();

  float zac0=0.f, zac1=0.f, zac2=0.f, zac3=0.f;
  for (int it=0; it<16; ++it){
    if (it+1 < 16){
      const char* kg = (const char*)kst + (size_t)(kspl*16+it+1)*16384;
      char* dst = smem + ((it+1)&1)*16384;
      #pragma unroll
      for (int i=0;i<4;i++)
        gld16(kg + (t + i*256)*16, dst + (t + i*256)*16);
    }
    const char* Kb = smem + (it&1)*16384;
    short8 ak[4];
    #pragma unroll
    for (int kk=0;kk<4;kk++)
      ak[kk] = *(const short8*)(Kb + ((w*4+kk)<<10) + lane*16);
    f32x4 s0={0,0,0,0}, s1={0,0,0,0}, s2={0,0,0,0}, s3={0,0,0,0};
    #pragma unroll
    for (int kk=0; kk<4; ++kk){
      s0 = __builtin_amdgcn_mfma_f32_16x16x32_bf16(ak[kk], qf[0][kk], s0, 0, 0, 0);
      s1 = __builtin_amdgcn_mfma_f32_16x16x32_bf16(ak[kk], qf[1][kk], s1, 0, 0, 0);
      s2 = __builtin_amdgcn_mfma_f32_16x16x32_bf16(ak[kk], qf[2][kk], s2, 0, 0, 0);
      s3 = __builtin_amdgcn_mfma_f32_16x16x32_bf16(ak[kk], qf[3][kk], s3, 0, 0, 0);
    }
    #pragma unroll
    for (int j=0;j<4;j++){
      zac0 += __builtin_exp2f(s0[j]);
      zac1 += __builtin_exp2f(s1[j]);
      zac2 += __builtin_exp2f(s2[j]);
      zac3 += __builtin_exp2f(s3[j]);
    }
    __syncthreads();
  }
  zac0 += __shfl_xor(zac0,16); zac0 += __shfl_xor(zac0,32);
  zac1 += __shfl_xor(zac1,16); zac1 += __shfl_xor(zac1,32);
  zac2 += __shfl_xor(zac2,16); zac2 += __shfl_xor(zac2,32);
  zac3 += __shfl_xor(zac3,16); zac3 += __shfl_xor(zac3,32);
  float* zred = (float*)(smem + 32768);
  if (lane < 16){
    zred[w*64 + 0*16 + lane] = zac0;
    zred[w*64 + 1*16 + lane] = zac1;
    zred[w*64 + 2*16 + lane] = zac2;
    zred[w*64 + 3*16 + lane] = zac3;
  }
  __syncthreads();
  if (t < 64){
    float z = zred[t] + zred[64+t] + zred[128+t] + zred[192+t];
    zpart[(size_t)kspl*SQ + qs*64 + t] = z;
  }
}

// ---------------------------------------------------------------------------
// prep_v: runs AFTER kz. Vt[q,:] = V[q,:] / Z_q, written as V stream records.
// ---------------------------------------------------------------------------
__global__ __launch_bounds__(256) void prep_v(const float* __restrict__ Vp,
                                              const float* __restrict__ zpart,
                                              ushort_t* __restrict__ vst){
  __shared__ ushort_t vl[64][132];
  int tile = blockIdx.x;    // 0..127
  int t = threadIdx.x;
  int q = t >> 2, dvb4 = (t & 3)*32;
  float z = 0.f;
  #pragma unroll
  for (int s=0;s<ZSPLIT;s++) z += zpart[(size_t)s*SQ + tile*64 + q];
  float vinv = 1.0f / z;
  const float* src = Vp + (size_t)(tile*64 + q)*DD + dvb4;
  #pragma unroll
  for (int j=0;j<8;j++){
    float4 f = ((const float4*)src)[j];
    vl[q][dvb4 + j*4 + 0] = f2bf(f.x*vinv);
    vl[q][dvb4 + j*4 + 1] = f2bf(f.y*vinv);
    vl[q][dvb4 + j*4 + 2] = f2bf(f.z*vinv);
    vl[q][dvb4 + j*4 + 3] = f2bf(f.w*vinv);
  }
  __syncthreads();
  char* obase = (char*)vst + (size_t)tile*16384;
  #pragma unroll
  for (int s2=0;s2<4;s2++){
    int sid = t*4 + s2;                 // 0..1023 = rec*64 + lane
    int rec = sid >> 6, lr = sid & 63;
    int dv = (rec & 7)*16 + (lr & 15);
    int qb = (rec >> 3)*32 + (lr >> 4)*8;
    unsigned int wv[4];
    #pragma unroll
    for (int p=0;p<4;p++){
      unsigned lo = vl[qb + p*2 + 0][dv];
      unsigned hi = vl[qb + p*2 + 1][dv];
      wv[p] = lo | (hi << 16);
    }
    ((uint4*)(obase + rec*1024 + lr*16))[0] = make_uint4(wv[0],wv[1],wv[2],wv[3]);
  }
}

// ---------------------------------------------------------------------------
// ko: BARRIER-FREE, LDS-FREE fused main pass. P~ = exp2(s); V~ = V/Z.
// Grid = 64 ktiles x 8 qsp = 512 WGs x 256 thr (4 waves). Wave kg owns
// 32 k-rows (kf[2][4] from K stream, once). Per 64-q tile: 16 coalesced
// Q-record loads -> 32 G1 MFMAs -> exp2/pack/permlane -> 16 V-record
// loads -> 32 PV MFMAs. Intra-block 4x record redundancy served by L1;
// qsp-peer blocks sit on one XCD (wgid%8 = ktile%8) so streams and the
// atomic out-tile stay L2-local. Waves free-run: no phase coupling.
// ---------------------------------------------------------------------------
__global__ __launch_bounds__(256) void ko(const ushort_t* __restrict__ kst,
                                          const ushort_t* __restrict__ qst,
                                          const ushort_t* __restrict__ vst,
                                          float* __restrict__ out){
  int wg = blockIdx.x;            // 512
  int ktile = wg & 63;            // xcd = ktile%8
  int qsp   = wg >> 6;            // 0..7
  int t = threadIdx.x, lane = t & 63, kg = t >> 6;   // kg in 0..3
  int r15 = lane & 15, g4 = lane >> 4;

  // kf: wave's 32 k-rows from the K stream (one-time, coalesced)
  short8 kf[2][4];
  { const char* kb = (const char*)kst + (size_t)(ktile*2 + (kg>>1))*16384;
    int rg0 = (kg & 1)*2;
    #pragma unroll
    for (int b=0;b<2;b++)
      #pragma unroll
      for (int kk=0;kk<4;kk++)
        kf[b][kk] = *(const short8*)(kb + (((rg0+b)*4+kk)<<10) + lane*16);
  }

  f32x4 zero = {0.f,0.f,0.f,0.f};
  f32x4 acc[2][8];
  #pragma unroll
  for (int b=0;b<2;b++)
    #pragma unroll
    for (int i=0;i<8;i++) acc[b][i] = zero;

  const char* qb = (const char*)qst + (size_t)(qsp*16)*16384;
  const char* vb = (const char*)vst + (size_t)(qsp*16)*16384;

  for (int it=0; it<16; ++it, qb += 16384, vb += 16384){
    short8 af[2][2];                 // [qc][b]
    #pragma unroll
    for (int qc=0; qc<2; ++qc){
      unsigned pw[2][4];
      #pragma unroll
      for (int blk=0; blk<2; ++blk){
        short8 aq[4];
        #pragma unroll
        for (int kk=0; kk<4; ++kk)
          aq[kk] = *(const short8*)(qb + (((qc*2+blk)*4+kk)<<10) + lane*16);
        f32x4 s0 = {0.f,0.f,0.f,0.f};
        f32x4 s1 = {0.f,0.f,0.f,0.f};
        #pragma unroll
        for (int kk=0; kk<4; ++kk){
          s0 = __builtin_amdgcn_mfma_f32_16x16x32_bf16(aq[kk], kf[0][kk], s0, 0, 0, 0);
          s1 = __builtin_amdgcn_mfma_f32_16x16x32_bf16(aq[kk], kf[1][kk], s1, 0, 0, 0);
        }
        #pragma unroll
        for (int b=0;b<2;b++){
          f32x4 s = b ? s1 : s0;
          float p0 = __builtin_exp2f(s[0]);
          float p1 = __builtin_exp2f(s[1]);
          float p2 = __builtin_exp2f(s[2]);
          float p3 = __builtin_exp2f(s[3]);
          unsigned wa, wb;
          asm("v_cvt_pk_bf16_f32 %0, %1, %2" : "=v"(wa) : "v"(p0), "v"(p1));
          asm("v_cvt_pk_bf16_f32 %0, %1, %2" : "=v"(wb) : "v"(p2), "v"(p3));
          pw[b][blk*2+0] = wa;
          pw[b][blk*2+1] = wb;
        }
      }
      #pragma unroll
      for (int b=0;b<2;b++){
        asm("v_permlane32_swap_b32 %0, %1" : "+v"(pw[b][0]), "+v"(pw[b][2]));
        asm("v_permlane32_swap_b32 %0, %1" : "+v"(pw[b][1]), "+v"(pw[b][3]));
        asm("v_permlane16_swap_b32 %0, %1" : "+v"(pw[b][0]), "+v"(pw[b][2]));
        asm("v_permlane16_swap_b32 %0, %1" : "+v"(pw[b][1]), "+v"(pw[b][3]));
        uint4v fw = { pw[b][0], pw[b][1], pw[b][2], pw[b][3] };
        af[qc][b] = __builtin_bit_cast(short8, fw);
      }
    }
    // ---- PV: O += P~.V~ (V records coalesced from stream) ----
    #pragma unroll
    for (int qc=0; qc<2; ++qc){
      #pragma unroll
      for (int dvb=0; dvb<8; ++dvb){
        short8 bv = *(const short8*)(vb + ((qc*8+dvb)<<10) + lane*16);
        acc[0][dvb] = __builtin_amdgcn_mfma_f32_16x16x32_bf16(af[qc][0], bv, acc[0][dvb], 0, 0, 0);
        acc[1][dvb] = __builtin_amdgcn_mfma_f32_16x16x32_bf16(af[qc][1], bv, acc[1][dvb], 0, 0, 0);
      }
    }
  }
  // ---- epilogue: accumulate across the 8 q-split WGs (XCD-local) ----
  #pragma unroll
  for (int b=0;b<2;b++)
    #pragma unroll
    for (int dvb=0; dvb<8; ++dvb)
      #pragma unroll
      for (int j=0;j<4;j++){
        int k  = ktile*128 + kg*32 + b*16 + g4*4 + j;
        int dv = dvb*16 + r15;
        atomicAdd(out + (size_t)k*DD + dv, acc[b][dvb][j]);
      }
}

extern "C" void kernel_launch(void* const* d_in, const int* in_sizes, int n_in,
                              void* d_out, int out_size, void* d_ws, size_t ws_size,
                              hipStream_t stream) {
  const float* Kp = (const float*)d_in[0];
  const float* Qp = (const float*)d_in[1];
  const float* Vp = (const float*)d_in[2];
  float* out = (float*)d_out;
  char* ws = (char*)d_ws;
  ushort_t* kst  = (ushort_t*)ws;
  ushort_t* qst  = (ushort_t*)(ws + ((size_t)2<<20));
  ushort_t* vst  = (ushort_t*)(ws + ((size_t)4<<20));
  float* zpart   = (float*)(ws + ((size_t)6<<20));

  hipMemsetAsync(d_out, 0, (size_t)SK*DD*sizeof(float), stream);
  prep_kq<<<dim3(1024), dim3(256), 0, stream>>>(Kp, Qp, kst, qst);
  kz     <<<dim3(1024), dim3(256), 0, stream>>>(kst, qst, zpart);
  prep_v <<<dim3(128),  dim3(256), 0, stream>>>(Vp, zpart, vst);
  ko     <<<dim3(512),  dim3(256), 0, stream>>>(kst, qst, vst, out);
}

// Round 11
// 103.683 us; speedup vs baseline: 1.3982x; 1.3982x over previous
//
#include <hip/hip_runtime.h>

#define SK 8192
#define SQ 8192
#define DD 128
#define ZSPLIT 8

typedef __attribute__((ext_vector_type(8))) short short8;
typedef __attribute__((ext_vector_type(4))) float f32x4;
typedef __attribute__((ext_vector_type(4))) unsigned uint4v;
typedef unsigned short ushort_t;

// round-to-nearest-even f32 -> bf16
__device__ __forceinline__ unsigned short f2bf(float x){
  unsigned int u = __float_as_uint(x);
  u += 0x7FFFu + ((u >> 16) & 1u);
  return (unsigned short)(u >> 16);
}

// async global->LDS DMA, 16B/lane. LDS dest = uniform base + lane*16.
__device__ __forceinline__ void gld16(const void* g, void* l){
  __builtin_amdgcn_global_load_lds(
      (const __attribute__((address_space(1))) unsigned int*)g,
      (__attribute__((address_space(3))) unsigned int*)l, 16, 0, 0);
}

// ---------------------------------------------------------------------------
// STREAM LAYOUTS (fragment-record form; all reads are coalesced 1KB records)
// K/Q stream: per 64-row tile, 16 records of 1KB; rec = rg*4 + kk.
//   Lane l, byte pair j: element M[tile*64 + rg*16 + (l&15)][kk*32 + (l>>4)*8 + j]
// V stream: per 64-q tile, 16 records; rec = qc*8 + dvb. Lane l:
//   element V^T[dvb*16 + (l&15)][qc*32 + (l>>4)*8 + j]  (V^T pre-scaled 1/Z)
// ---------------------------------------------------------------------------

// prep_kq: cast K (pre-scaled by log2(e)/sqrt(128)) and Q to bf16 streams.
__global__ __launch_bounds__(256) void prep_kq(const float* __restrict__ Kp,
                                               const float* __restrict__ Qp,
                                               ushort_t* __restrict__ kst,
                                               ushort_t* __restrict__ qst){
  int g = blockIdx.x*256 + threadIdx.x;
  int arr = g >> 17;
  int s   = g & 131071;
  int row = s >> 4;
  int c16 = s & 15;            // 8-elem slot: d = c16*8..c16*8+7
  const float* src = (arr ? Qp : Kp) + row*DD + c16*8;
  const float scale = arr ? 1.0f : 0.12751743f;   // log2(e)/sqrt(128)
  float4 f0 = ((const float4*)src)[0];
  float4 f1 = ((const float4*)src)[1];
  unsigned int wv[4];
  wv[0] = (unsigned)f2bf(f0.x*scale) | ((unsigned)f2bf(f0.y*scale) << 16);
  wv[1] = (unsigned)f2bf(f0.z*scale) | ((unsigned)f2bf(f0.w*scale) << 16);
  wv[2] = (unsigned)f2bf(f1.x*scale) | ((unsigned)f2bf(f1.y*scale) << 16);
  wv[3] = (unsigned)f2bf(f1.z*scale) | ((unsigned)f2bf(f1.w*scale) << 16);
  ushort_t* base = arr ? qst : kst;
  int tile = row >> 6, rg = (row >> 4) & 3, r15 = row & 15;
  int kk = c16 >> 2, g4 = c16 & 3;
  char* dst = (char*)base + (size_t)tile*16384 + (rg*4 + kk)*1024 + (g4*16 + r15)*16;
  ((uint4*)dst)[0] = make_uint4(wv[0],wv[1],wv[2],wv[3]);
}

// ---------------------------------------------------------------------------
// kz: per-column stats (unchanged from r10 — passing). K staged linear +
// dbuf; records conflict-free; Q-frags coalesced from stream into regs.
// ---------------------------------------------------------------------------
__global__ __launch_bounds__(256, 4) void kz(const ushort_t* __restrict__ kst,
                                             const ushort_t* __restrict__ qst,
                                             float* __restrict__ zpart){
  __shared__ __align__(16) char smem[33792];   // K dbuf 2x16KB | zred 1KB
  int wg = blockIdx.x;            // 1024
  int qs   = wg >> 3;             // 0..127 (64-q stripe)
  int kspl = wg & 7;
  int t = threadIdx.x, lane = t & 63, w = t >> 6;   // w in 0..3
  int r15 = lane & 15, g4 = lane >> 4;

  { const char* kg = (const char*)kst + (size_t)(kspl*16)*16384;
    #pragma unroll
    for (int i=0;i<4;i++)
      gld16(kg + (t + i*256)*16, smem + (t + i*256)*16);
  }
  short8 qf[4][4];
  { const char* qg = (const char*)qst + (size_t)qs*16384;
    #pragma unroll
    for (int qg_=0; qg_<4; ++qg_)
      #pragma unroll
      for (int kk=0; kk<4; ++kk)
        qf[qg_][kk] = *(const short8*)(qg + ((qg_*4+kk)<<10) + lane*16);
  }
  __syncthreads();

  float zac0=0.f, zac1=0.f, zac2=0.f, zac3=0.f;
  for (int it=0; it<16; ++it){
    if (it+1 < 16){
      const char* kg = (const char*)kst + (size_t)(kspl*16+it+1)*16384;
      char* dst = smem + ((it+1)&1)*16384;
      #pragma unroll
      for (int i=0;i<4;i++)
        gld16(kg + (t + i*256)*16, dst + (t + i*256)*16);
    }
    const char* Kb = smem + (it&1)*16384;
    short8 ak[4];
    #pragma unroll
    for (int kk=0;kk<4;kk++)
      ak[kk] = *(const short8*)(Kb + ((w*4+kk)<<10) + lane*16);
    f32x4 s0={0,0,0,0}, s1={0,0,0,0}, s2={0,0,0,0}, s3={0,0,0,0};
    #pragma unroll
    for (int kk=0; kk<4; ++kk){
      s0 = __builtin_amdgcn_mfma_f32_16x16x32_bf16(ak[kk], qf[0][kk], s0, 0, 0, 0);
      s1 = __builtin_amdgcn_mfma_f32_16x16x32_bf16(ak[kk], qf[1][kk], s1, 0, 0, 0);
      s2 = __builtin_amdgcn_mfma_f32_16x16x32_bf16(ak[kk], qf[2][kk], s2, 0, 0, 0);
      s3 = __builtin_amdgcn_mfma_f32_16x16x32_bf16(ak[kk], qf[3][kk], s3, 0, 0, 0);
    }
    #pragma unroll
    for (int j=0;j<4;j++){
      zac0 += __builtin_exp2f(s0[j]);
      zac1 += __builtin_exp2f(s1[j]);
      zac2 += __builtin_exp2f(s2[j]);
      zac3 += __builtin_exp2f(s3[j]);
    }
    __syncthreads();
  }
  zac0 += __shfl_xor(zac0,16); zac0 += __shfl_xor(zac0,32);
  zac1 += __shfl_xor(zac1,16); zac1 += __shfl_xor(zac1,32);
  zac2 += __shfl_xor(zac2,16); zac2 += __shfl_xor(zac2,32);
  zac3 += __shfl_xor(zac3,16); zac3 += __shfl_xor(zac3,32);
  float* zred = (float*)(smem + 32768);
  if (lane < 16){
    zred[w*64 + 0*16 + lane] = zac0;
    zred[w*64 + 1*16 + lane] = zac1;
    zred[w*64 + 2*16 + lane] = zac2;
    zred[w*64 + 3*16 + lane] = zac3;
  }
  __syncthreads();
  if (t < 64){
    float z = zred[t] + zred[64+t] + zred[128+t] + zred[192+t];
    zpart[(size_t)kspl*SQ + qs*64 + t] = z;
  }
}

// ---------------------------------------------------------------------------
// prep_v: runs AFTER kz. Vt[q,:] = V[q,:] / Z_q, written as V stream records.
// ---------------------------------------------------------------------------
__global__ __launch_bounds__(256) void prep_v(const float* __restrict__ Vp,
                                              const float* __restrict__ zpart,
                                              ushort_t* __restrict__ vst){
  __shared__ ushort_t vl[64][132];
  int tile = blockIdx.x;    // 0..127
  int t = threadIdx.x;
  int q = t >> 2, dvb4 = (t & 3)*32;
  float z = 0.f;
  #pragma unroll
  for (int s=0;s<ZSPLIT;s++) z += zpart[(size_t)s*SQ + tile*64 + q];
  float vinv = 1.0f / z;
  const float* src = Vp + (size_t)(tile*64 + q)*DD + dvb4;
  #pragma unroll
  for (int j=0;j<8;j++){
    float4 f = ((const float4*)src)[j];
    vl[q][dvb4 + j*4 + 0] = f2bf(f.x*vinv);
    vl[q][dvb4 + j*4 + 1] = f2bf(f.y*vinv);
    vl[q][dvb4 + j*4 + 2] = f2bf(f.z*vinv);
    vl[q][dvb4 + j*4 + 3] = f2bf(f.w*vinv);
  }
  __syncthreads();
  char* obase = (char*)vst + (size_t)tile*16384;
  #pragma unroll
  for (int s2=0;s2<4;s2++){
    int sid = t*4 + s2;                 // 0..1023 = rec*64 + lane
    int rec = sid >> 6, lr = sid & 63;
    int dv = (rec & 7)*16 + (lr & 15);
    int qb = (rec >> 3)*32 + (lr >> 4)*8;
    unsigned int wv[4];
    #pragma unroll
    for (int p=0;p<4;p++){
      unsigned lo = vl[qb + p*2 + 0][dv];
      unsigned hi = vl[qb + p*2 + 1][dv];
      wv[p] = lo | (hi << 16);
    }
    ((uint4*)(obase + rec*1024 + lr*16))[0] = make_uint4(wv[0],wv[1],wv[2],wv[3]);
  }
}

// ---------------------------------------------------------------------------
// ko: fused main pass at HIGH RESIDENCY. Grid = 64 ktiles x 8 qsp = 512
// WGs x 1024 thr (16 waves = 8 k-groups x 2 q-halves) -> 2 blocks/CU,
// ~20+ waves/CU (VGPR-capped), atomics stay at the 8-split level.
// Wave (kg,qh): 16 k-rows vs its 32-q half. Per 64-q tile: 8 record
// ds_reads -> 8 G1 MFMAs -> exp2/pack/permlane (r9-proven algebra) ->
// 8 record ds_reads -> 8 PV MFMAs. LDS: Q16K+V16K double-buffered
// (linear records, conflict-free), 1 barrier/iter. Epilogue: q-half
// pair LDS-reduce, qh=0 issues atomics. XCD map: wgid%8 == ktile%8.
// ---------------------------------------------------------------------------
__global__ __launch_bounds__(1024) void ko(const ushort_t* __restrict__ kst,
                                           const ushort_t* __restrict__ qst,
                                           const ushort_t* __restrict__ vst,
                                           float* __restrict__ out){
  __shared__ __align__(16) char smem[65536];   // dbuf 2 x (Q 16K + V 16K)
  int wg = blockIdx.x;            // 512
  int ktile = wg & 63;            // xcd = ktile%8: qsp-mates share an XCD
  int qsp   = wg >> 6;            // 0..7
  int t = threadIdx.x, lane = t & 63, w = t >> 6;   // w in 0..15
  int kg = w & 7, qh = w >> 3;
  int r15 = lane & 15, g4 = lane >> 4;

  // ---- prologue: stage K (32KB) into smem, hoist kf, then Q0/V0 ----
  { const char* kgp = (const char*)kst + (size_t)ktile*32768;
    #pragma unroll
    for (int i=0;i<2;i++)
      gld16(kgp + (t + i*1024)*16, smem + (t + i*1024)*16);
  }
  __syncthreads();
  short8 kf[4];
  { const char* kb = smem + (kg>>2)*16384;
    int rg = kg & 3;
    #pragma unroll
    for (int kk=0;kk<4;kk++)
      kf[kk] = *(const short8*)(kb + ((rg*4+kk)<<10) + lane*16);
  }
  __syncthreads();
  { const char* qg = (const char*)qst + (size_t)(qsp*16)*16384;
    const char* vg = (const char*)vst + (size_t)(qsp*16)*16384;
    gld16(qg + t*16, smem + t*16);
    gld16(vg + t*16, smem + 16384 + t*16);
  }

  f32x4 zero = {0.f,0.f,0.f,0.f};
  f32x4 acc[8];
  #pragma unroll
  for (int i=0;i<8;i++) acc[i] = zero;

  for (int it=0; it<16; ++it){
    __syncthreads();                 // buf(it) DMA drained; buf(it^1) free
    const char* Qb = smem + (it&1)*32768;
    const char* Vb = Qb + 16384;
    // prefetch next Q/V into other buffer (drained at next barrier)
    if (it+1 < 16){
      const char* qg = (const char*)qst + (size_t)(qsp*16+it+1)*16384;
      const char* vg = (const char*)vst + (size_t)(qsp*16+it+1)*16384;
      char* dst = smem + ((it+1)&1)*32768;
      gld16(qg + t*16, dst + t*16);
      gld16(vg + t*16, dst + 16384 + t*16);
    }
    // ---- G1: S^T for wave's 16 k-rows x its 32-q half ----
    unsigned pw[4];
    #pragma unroll
    for (int blk=0; blk<2; ++blk){
      short8 aq[4];
      #pragma unroll
      for (int kk=0; kk<4; ++kk)
        aq[kk] = *(const short8*)(Qb + (((qh*2+blk)*4+kk)<<10) + lane*16);
      f32x4 s = {0.f,0.f,0.f,0.f};
      #pragma unroll
      for (int kk=0; kk<4; ++kk)
        s = __builtin_amdgcn_mfma_f32_16x16x32_bf16(aq[kk], kf[kk], s, 0, 0, 0);
      float p0 = __builtin_exp2f(s[0]);
      float p1 = __builtin_exp2f(s[1]);
      float p2 = __builtin_exp2f(s[2]);
      float p3 = __builtin_exp2f(s[3]);
      unsigned wa, wb;
      asm("v_cvt_pk_bf16_f32 %0, %1, %2" : "=v"(wa) : "v"(p0), "v"(p1));
      asm("v_cvt_pk_bf16_f32 %0, %1, %2" : "=v"(wb) : "v"(p2), "v"(p3));
      pw[blk*2+0] = wa;
      pw[blk*2+1] = wb;
    }
    asm("v_permlane32_swap_b32 %0, %1" : "+v"(pw[0]), "+v"(pw[2]));
    asm("v_permlane32_swap_b32 %0, %1" : "+v"(pw[1]), "+v"(pw[3]));
    asm("v_permlane16_swap_b32 %0, %1" : "+v"(pw[0]), "+v"(pw[2]));
    asm("v_permlane16_swap_b32 %0, %1" : "+v"(pw[1]), "+v"(pw[3]));
    uint4v fw = { pw[0], pw[1], pw[2], pw[3] };
    short8 af = __builtin_bit_cast(short8, fw);
    // ---- PV: O += P~.V~ for wave's q-half ----
    __builtin_amdgcn_s_setprio(1);
    #pragma unroll
    for (int dvb=0; dvb<8; ++dvb){
      short8 bv = *(const short8*)(Vb + ((qh*8+dvb)<<10) + lane*16);
      acc[dvb] = __builtin_amdgcn_mfma_f32_16x16x32_bf16(af, bv, acc[dvb], 0, 0, 0);
    }
    __builtin_amdgcn_s_setprio(0);
  }
  // ---- epilogue: reduce q-half pair via LDS, then atomics (qh=0 only) ----
  __syncthreads();                   // all waves done with buffers
  f32x4* red = (f32x4*)smem;         // [dvb 0..7][kg*64+lane]  (64KB)
  if (qh == 1){
    #pragma unroll
    for (int dvb=0; dvb<8; ++dvb)
      red[dvb*512 + kg*64 + lane] = acc[dvb];
  }
  __syncthreads();
  if (qh == 0){
    #pragma unroll
    for (int dvb=0; dvb<8; ++dvb){
      f32x4 o = red[dvb*512 + kg*64 + lane];
      f32x4 a = acc[dvb];
      #pragma unroll
      for (int j=0;j<4;j++){
        int k  = ktile*128 + kg*16 + g4*4 + j;
        int dv = dvb*16 + r15;
        atomicAdd(out + (size_t)k*DD + dv, a[j] + o[j]);
      }
    }
  }
}

extern "C" void kernel_launch(void* const* d_in, const int* in_sizes, int n_in,
                              void* d_out, int out_size, void* d_ws, size_t ws_size,
                              hipStream_t stream) {
  const float* Kp = (const float*)d_in[0];
  const float* Qp = (const float*)d_in[1];
  const float* Vp = (const float*)d_in[2];
  float* out = (float*)d_out;
  char* ws = (char*)d_ws;
  ushort_t* kst  = (ushort_t*)ws;
  ushort_t* qst  = (ushort_t*)(ws + ((size_t)2<<20));
  ushort_t* vst  = (ushort_t*)(ws + ((size_t)4<<20));
  float* zpart   = (float*)(ws + ((size_t)6<<20));

  hipMemsetAsync(d_out, 0, (size_t)SK*DD*sizeof(float), stream);
  prep_kq<<<dim3(1024), dim3(256), 0, stream>>>(Kp, Qp, kst, qst);
  kz     <<<dim3(1024), dim3(256), 0, stream>>>(kst, qst, zpart);
  prep_v <<<dim3(128),  dim3(256), 0, stream>>>(Vp, zpart, vst);
  ko     <<<dim3(512),  dim3(1024), 0, stream>>>(kst, qst, vst, out);
}

// Round 13
// 103.179 us; speedup vs baseline: 1.4051x; 1.0049x over previous
//
#include <hip/hip_runtime.h>

#define SK 8192
#define SQ 8192
#define DD 128
#define ZSPLIT 8

typedef __attribute__((ext_vector_type(8))) short short8;
typedef __attribute__((ext_vector_type(4))) float f32x4;
typedef __attribute__((ext_vector_type(4))) unsigned uint4v;
typedef unsigned short ushort_t;

// round-to-nearest-even f32 -> bf16
__device__ __forceinline__ unsigned short f2bf(float x){
  unsigned int u = __float_as_uint(x);
  u += 0x7FFFu + ((u >> 16) & 1u);
  return (unsigned short)(u >> 16);
}

// async global->LDS DMA, 16B/lane. LDS dest = uniform base + lane*16.
__device__ __forceinline__ void gld16(const void* g, void* l){
  __builtin_amdgcn_global_load_lds(
      (const __attribute__((address_space(1))) unsigned int*)g,
      (__attribute__((address_space(3))) unsigned int*)l, 16, 0, 0);
}

// ---------------------------------------------------------------------------
// STREAM LAYOUTS (fragment-record form; all reads are coalesced 1KB records)
// K/Q stream: per 64-row tile, 16 records of 1KB; rec = rg*4 + kk.
//   Lane l, byte pair j: element M[tile*64 + rg*16 + (l&15)][kk*32 + (l>>4)*8 + j]
// V stream: per 64-q tile, 16 records; rec = qc*8 + dvb. Lane l:
//   element V^T[dvb*16 + (l&15)][qc*32 + (l>>4)*8 + j]  (V^T pre-scaled 1/Z)
// ---------------------------------------------------------------------------

// prep_kq: cast K (pre-scaled by log2(e)/sqrt(128)) and Q to bf16 streams.
__global__ __launch_bounds__(256) void prep_kq(const float* __restrict__ Kp,
                                               const float* __restrict__ Qp,
                                               ushort_t* __restrict__ kst,
                                               ushort_t* __restrict__ qst){
  int g = blockIdx.x*256 + threadIdx.x;
  int arr = g >> 17;
  int s   = g & 131071;
  int row = s >> 4;
  int c16 = s & 15;            // 8-elem slot: d = c16*8..c16*8+7
  const float* src = (arr ? Qp : Kp) + row*DD + c16*8;
  const float scale = arr ? 1.0f : 0.12751743f;   // log2(e)/sqrt(128)
  float4 f0 = ((const float4*)src)[0];
  float4 f1 = ((const float4*)src)[1];
  unsigned int wv[4];
  wv[0] = (unsigned)f2bf(f0.x*scale) | ((unsigned)f2bf(f0.y*scale) << 16);
  wv[1] = (unsigned)f2bf(f0.z*scale) | ((unsigned)f2bf(f0.w*scale) << 16);
  wv[2] = (unsigned)f2bf(f1.x*scale) | ((unsigned)f2bf(f1.y*scale) << 16);
  wv[3] = (unsigned)f2bf(f1.z*scale) | ((unsigned)f2bf(f1.w*scale) << 16);
  ushort_t* base = arr ? qst : kst;
  int tile = row >> 6, rg = (row >> 4) & 3, r15 = row & 15;
  int kk = c16 >> 2, g4 = c16 & 3;
  char* dst = (char*)base + (size_t)tile*16384 + (rg*4 + kk)*1024 + (g4*16 + r15)*16;
  ((uint4*)dst)[0] = make_uint4(wv[0],wv[1],wv[2],wv[3]);
}

// ---------------------------------------------------------------------------
// kz: per-column stats (unchanged — passing since r10). K staged linear +
// dbuf; records conflict-free; Q-frags coalesced from stream into regs.
// ---------------------------------------------------------------------------
__global__ __launch_bounds__(256, 4) void kz(const ushort_t* __restrict__ kst,
                                             const ushort_t* __restrict__ qst,
                                             float* __restrict__ zpart){
  __shared__ __align__(16) char smem[33792];   // K dbuf 2x16KB | zred 1KB
  int wg = blockIdx.x;            // 1024
  int qs   = wg >> 3;             // 0..127 (64-q stripe)
  int kspl = wg & 7;
  int t = threadIdx.x, lane = t & 63, w = t >> 6;   // w in 0..3
  int r15 = lane & 15, g4 = lane >> 4;

  { const char* kg = (const char*)kst + (size_t)(kspl*16)*16384;
    #pragma unroll
    for (int i=0;i<4;i++)
      gld16(kg + (t + i*256)*16, smem + (t + i*256)*16);
  }
  short8 qf[4][4];
  { const char* qg = (const char*)qst + (size_t)qs*16384;
    #pragma unroll
    for (int qg_=0; qg_<4; ++qg_)
      #pragma unroll
      for (int kk=0; kk<4; ++kk)
        qf[qg_][kk] = *(const short8*)(qg + ((qg_*4+kk)<<10) + lane*16);
  }
  __syncthreads();

  float zac0=0.f, zac1=0.f, zac2=0.f, zac3=0.f;
  for (int it=0; it<16; ++it){
    if (it+1 < 16){
      const char* kg = (const char*)kst + (size_t)(kspl*16+it+1)*16384;
      char* dst = smem + ((it+1)&1)*16384;
      #pragma unroll
      for (int i=0;i<4;i++)
        gld16(kg + (t + i*256)*16, dst + (t + i*256)*16);
    }
    const char* Kb = smem + (it&1)*16384;
    short8 ak[4];
    #pragma unroll
    for (int kk=0;kk<4;kk++)
      ak[kk] = *(const short8*)(Kb + ((w*4+kk)<<10) + lane*16);
    f32x4 s0={0,0,0,0}, s1={0,0,0,0}, s2={0,0,0,0}, s3={0,0,0,0};
    #pragma unroll
    for (int kk=0; kk<4; ++kk){
      s0 = __builtin_amdgcn_mfma_f32_16x16x32_bf16(ak[kk], qf[0][kk], s0, 0, 0, 0);
      s1 = __builtin_amdgcn_mfma_f32_16x16x32_bf16(ak[kk], qf[1][kk], s1, 0, 0, 0);
      s2 = __builtin_amdgcn_mfma_f32_16x16x32_bf16(ak[kk], qf[2][kk], s2, 0, 0, 0);
      s3 = __builtin_amdgcn_mfma_f32_16x16x32_bf16(ak[kk], qf[3][kk], s3, 0, 0, 0);
    }
    #pragma unroll
    for (int j=0;j<4;j++){
      zac0 += __builtin_exp2f(s0[j]);
      zac1 += __builtin_exp2f(s1[j]);
      zac2 += __builtin_exp2f(s2[j]);
      zac3 += __builtin_exp2f(s3[j]);
    }
    __syncthreads();
  }
  zac0 += __shfl_xor(zac0,16); zac0 += __shfl_xor(zac0,32);
  zac1 += __shfl_xor(zac1,16); zac1 += __shfl_xor(zac1,32);
  zac2 += __shfl_xor(zac2,16); zac2 += __shfl_xor(zac2,32);
  zac3 += __shfl_xor(zac3,16); zac3 += __shfl_xor(zac3,32);
  float* zred = (float*)(smem + 32768);
  if (lane < 16){
    zred[w*64 + 0*16 + lane] = zac0;
    zred[w*64 + 1*16 + lane] = zac1;
    zred[w*64 + 2*16 + lane] = zac2;
    zred[w*64 + 3*16 + lane] = zac3;
  }
  __syncthreads();
  if (t < 64){
    float z = zred[t] + zred[64+t] + zred[128+t] + zred[192+t];
    zpart[(size_t)kspl*SQ + qs*64 + t] = z;
  }
}

// ---------------------------------------------------------------------------
// prep_v: runs AFTER kz. Vt[q,:] = V[q,:] / Z_q, written as V stream records.
// ---------------------------------------------------------------------------
__global__ __launch_bounds__(256) void prep_v(const float* __restrict__ Vp,
                                              const float* __restrict__ zpart,
                                              ushort_t* __restrict__ vst){
  __shared__ ushort_t vl[64][132];
  int tile = blockIdx.x;    // 0..127
  int t = threadIdx.x;
  int q = t >> 2, dvb4 = (t & 3)*32;
  float z = 0.f;
  #pragma unroll
  for (int s=0;s<ZSPLIT;s++) z += zpart[(size_t)s*SQ + tile*64 + q];
  float vinv = 1.0f / z;
  const float* src = Vp + (size_t)(tile*64 + q)*DD + dvb4;
  #pragma unroll
  for (int j=0;j<8;j++){
    float4 f = ((const float4*)src)[j];
    vl[q][dvb4 + j*4 + 0] = f2bf(f.x*vinv);
    vl[q][dvb4 + j*4 + 1] = f2bf(f.y*vinv);
    vl[q][dvb4 + j*4 + 2] = f2bf(f.z*vinv);
    vl[q][dvb4 + j*4 + 3] = f2bf(f.w*vinv);
  }
  __syncthreads();
  char* obase = (char*)vst + (size_t)tile*16384;
  #pragma unroll
  for (int s2=0;s2<4;s2++){
    int sid = t*4 + s2;                 // 0..1023 = rec*64 + lane
    int rec = sid >> 6, lr = sid & 63;
    int dv = (rec & 7)*16 + (lr & 15);
    int qb = (rec >> 3)*32 + (lr >> 4)*8;
    unsigned int wv[4];
    #pragma unroll
    for (int p=0;p<4;p++){
      unsigned lo = vl[qb + p*2 + 0][dv];
      unsigned hi = vl[qb + p*2 + 1][dv];
      wv[p] = lo | (hi << 16);
    }
    ((uint4*)(obase + rec*1024 + lr*16))[0] = make_uint4(wv[0],wv[1],wv[2],wv[3]);
  }
}

// ---------------------------------------------------------------------------
// ko: R=4 amortization + deterministic-safe epilogue.
// Grid = 32 k-supertiles (256 rows) x 8 qsp = 256 WGs x 512 thr
// (8 waves = 4 k-groups x 2 q-halves). Wave (kg,qh): 64 k-rows (kf[4][4]
// read ONCE from the global K stream) vs its 32-q half. Each Q record
// feeds 4 G1 MFMAs, each V record feeds 4 PV MFMAs. LDS = Q16K+V16K
// double-buffer; 1 barrier/iter; 16 iters. Epilogue: q-half pair reduced
// DETERMINISTICALLY in LDS (two 64KB passes), then qh=0 issues atomics
// -> 8 adds/element (the historically tripwire-safe level).
// XCD map: wgid&31 = kt2 -> all 8 qsp-mates of an out-tile on one XCD.
// ---------------------------------------------------------------------------
__global__ __launch_bounds__(512, 2) void ko(const ushort_t* __restrict__ kst,
                                             const ushort_t* __restrict__ qst,
                                             const ushort_t* __restrict__ vst,
                                             float* __restrict__ out){
  __shared__ __align__(16) char smem[65536];   // dbuf 2 x (Q 16K + V 16K)
  int wg = blockIdx.x;            // 256
  int kt2 = wg & 31;              // 0..31 (256 k-rows); xcd = kt2%8
  int qsp = wg >> 5;              // 0..7  (16 q-tiles of 64)
  int t = threadIdx.x, lane = t & 63, w = t >> 6;   // w in 0..7
  int kg = w & 3, qh = w >> 2;
  int r15 = lane & 15, g4 = lane >> 4;

  // kf[kb][kk]: wave's 64 k-rows, one-time coalesced global reads
  short8 kf[4][4];
  { const char* kb = (const char*)kst + (size_t)(kt2*4 + kg)*16384;
    #pragma unroll
    for (int b=0;b<4;b++)
      #pragma unroll
      for (int kk=0;kk<4;kk++)
        kf[b][kk] = *(const short8*)(kb + ((b*4+kk)<<10) + lane*16);
  }
  // stage Q0/V0 into buf0
  { const char* qg = (const char*)qst + (size_t)(qsp*16)*16384;
    const char* vg = (const char*)vst + (size_t)(qsp*16)*16384;
    #pragma unroll
    for (int i=0;i<2;i++){
      gld16(qg + (t + i*512)*16, smem + (t + i*512)*16);
      gld16(vg + (t + i*512)*16, smem + 16384 + (t + i*512)*16);
    }
  }

  f32x4 zero = {0.f,0.f,0.f,0.f};
  f32x4 acc[4][8];
  #pragma unroll
  for (int b=0;b<4;b++)
    #pragma unroll
    for (int i=0;i<8;i++) acc[b][i] = zero;

  for (int it=0; it<16; ++it){
    __syncthreads();                 // buf(it) DMA drained; buf(it^1) free
    const char* Qb = smem + (it&1)*32768;
    const char* Vb = Qb + 16384;
    // prefetch next Q/V into other buffer (drained at next barrier)
    if (it+1 < 16){
      const char* qg = (const char*)qst + (size_t)(qsp*16+it+1)*16384;
      const char* vg = (const char*)vst + (size_t)(qsp*16+it+1)*16384;
      char* dst = smem + ((it+1)&1)*32768;
      #pragma unroll
      for (int i=0;i<2;i++){
        gld16(qg + (t + i*512)*16, dst + (t + i*512)*16);
        gld16(vg + (t + i*512)*16, dst + 16384 + (t + i*512)*16);
      }
    }
    // ---- G1: S^T for 4 k-blocks x wave's 32-q half ----
    unsigned pw[4][4];               // [kb][word]
    #pragma unroll
    for (int blk=0; blk<2; ++blk){
      f32x4 s[4];
      #pragma unroll
      for (int b=0;b<4;b++) s[b] = zero;
      #pragma unroll
      for (int kk=0; kk<4; ++kk){
        short8 aq = *(const short8*)(Qb + (((qh*2+blk)*4+kk)<<10) + lane*16);
        #pragma unroll
        for (int b=0;b<4;b++)
          s[b] = __builtin_amdgcn_mfma_f32_16x16x32_bf16(aq, kf[b][kk], s[b], 0, 0, 0);
      }
      #pragma unroll
      for (int b=0;b<4;b++){
        float p0 = __builtin_exp2f(s[b][0]);
        float p1 = __builtin_exp2f(s[b][1]);
        float p2 = __builtin_exp2f(s[b][2]);
        float p3 = __builtin_exp2f(s[b][3]);
        unsigned wa, wb;
        asm("v_cvt_pk_bf16_f32 %0, %1, %2" : "=v"(wa) : "v"(p0), "v"(p1));
        asm("v_cvt_pk_bf16_f32 %0, %1, %2" : "=v"(wb) : "v"(p2), "v"(p3));
        pw[b][blk*2+0] = wa;
        pw[b][blk*2+1] = wb;
      }
    }
    short8 af[4];
    #pragma unroll
    for (int b=0;b<4;b++){
      asm("v_permlane32_swap_b32 %0, %1" : "+v"(pw[b][0]), "+v"(pw[b][2]));
      asm("v_permlane32_swap_b32 %0, %1" : "+v"(pw[b][1]), "+v"(pw[b][3]));
      asm("v_permlane16_swap_b32 %0, %1" : "+v"(pw[b][0]), "+v"(pw[b][2]));
      asm("v_permlane16_swap_b32 %0, %1" : "+v"(pw[b][1]), "+v"(pw[b][3]));
      uint4v fw = { pw[b][0], pw[b][1], pw[b][2], pw[b][3] };
      af[b] = __builtin_bit_cast(short8, fw);
    }
    // ---- PV: each V record feeds all 4 k-blocks ----
    __builtin_amdgcn_s_setprio(1);
    #pragma unroll
    for (int dvb=0; dvb<8; ++dvb){
      short8 bv = *(const short8*)(Vb + ((qh*8+dvb)<<10) + lane*16);
      #pragma unroll
      for (int b=0;b<4;b++)
        acc[b][dvb] = __builtin_amdgcn_mfma_f32_16x16x32_bf16(af[b], bv, acc[b][dvb], 0, 0, 0);
    }
    __builtin_amdgcn_s_setprio(0);
  }
  // ---- epilogue: deterministic qh-pair reduce via LDS (2 x 64KB passes),
  //      then 8 atomics/element from qh=0 waves (XCD-local) ----
  f32x4* red = (f32x4*)smem;         // [b2*8+dvb][kg*64+lane]
  #pragma unroll
  for (int pass=0; pass<2; ++pass){
    __syncthreads();                 // buffers/prev-pass reads complete
    if (qh == 1){
      #pragma unroll
      for (int b2=0;b2<2;b2++)
        #pragma unroll
        for (int dvb=0; dvb<8; ++dvb)
          red[((b2*8 + dvb)<<8) + kg*64 + lane] = acc[pass*2+b2][dvb];
    }
    __syncthreads();
    if (qh == 0){
      #pragma unroll
      for (int b2=0;b2<2;b2++)
        #pragma unroll
        for (int dvb=0; dvb<8; ++dvb){
          f32x4 o = red[((b2*8 + dvb)<<8) + kg*64 + lane];
          f32x4 a = acc[pass*2+b2][dvb];
          #pragma unroll
          for (int j=0;j<4;j++){
            int k  = kt2*256 + kg*64 + (pass*2+b2)*16 + g4*4 + j;
            int dv = dvb*16 + r15;
            atomicAdd(out + (size_t)k*DD + dv, a[j] + o[j]);
          }
        }
    }
  }
}

extern "C" void kernel_launch(void* const* d_in, const int* in_sizes, int n_in,
                              void* d_out, int out_size, void* d_ws, size_t ws_size,
                              hipStream_t stream) {
  const float* Kp = (const float*)d_in[0];
  const float* Qp = (const float*)d_in[1];
  const float* Vp = (const float*)d_in[2];
  float* out = (float*)d_out;
  char* ws = (char*)d_ws;
  ushort_t* kst  = (ushort_t*)ws;
  ushort_t* qst  = (ushort_t*)(ws + ((size_t)2<<20));
  ushort_t* vst  = (ushort_t*)(ws + ((size_t)4<<20));
  float* zpart   = (float*)(ws + ((size_t)6<<20));

  hipMemsetAsync(d_out, 0, (size_t)SK*DD*sizeof(float), stream);
  prep_kq<<<dim3(1024), dim3(256), 0, stream>>>(Kp, Qp, kst, qst);
  kz     <<<dim3(1024), dim3(256), 0, stream>>>(kst, qst, zpart);
  prep_v <<<dim3(128),  dim3(256), 0, stream>>>(Vp, zpart, vst);
  ko     <<<dim3(256),  dim3(512), 0, stream>>>(kst, qst, vst, out);
}

// Round 14
// 101.284 us; speedup vs baseline: 1.4314x; 1.0187x over previous
//
#include <hip/hip_runtime.h>

#define SK 8192
#define SQ 8192
#define DD 128
#define ZSPLIT 8

typedef __attribute__((ext_vector_type(8))) short short8;
typedef __attribute__((ext_vector_type(4))) float f32x4;
typedef __attribute__((ext_vector_type(4))) unsigned uint4v;
typedef unsigned short ushort_t;

// round-to-nearest-even f32 -> bf16
__device__ __forceinline__ unsigned short f2bf(float x){
  unsigned int u = __float_as_uint(x);
  u += 0x7FFFu + ((u >> 16) & 1u);
  return (unsigned short)(u >> 16);
}

// async global->LDS DMA, 16B/lane. LDS dest = uniform base + lane*16.
__device__ __forceinline__ void gld16(const void* g, void* l){
  __builtin_amdgcn_global_load_lds(
      (const __attribute__((address_space(1))) unsigned int*)g,
      (__attribute__((address_space(3))) unsigned int*)l, 16, 0, 0);
}

// ---------------------------------------------------------------------------
// STREAM LAYOUTS (fragment-record form; all reads are coalesced 1KB records)
// K/Q stream: per 64-row tile, 16 records of 1KB; rec = rg*4 + kk.
//   Lane l, byte pair j: element M[tile*64 + rg*16 + (l&15)][kk*32 + (l>>4)*8 + j]
// V stream: per 64-q tile, 16 records; rec = qc*8 + dvb. Lane l:
//   element V^T[dvb*16 + (l&15)][qc*32 + (l>>4)*8 + j]  (V^T pre-scaled 1/Z)
// ---------------------------------------------------------------------------

// prep_kq: cast K (pre-scaled by log2(e)/sqrt(128)) and Q to bf16 streams.
__global__ __launch_bounds__(256) void prep_kq(const float* __restrict__ Kp,
                                               const float* __restrict__ Qp,
                                               ushort_t* __restrict__ kst,
                                               ushort_t* __restrict__ qst){
  int g = blockIdx.x*256 + threadIdx.x;
  int arr = g >> 17;
  int s   = g & 131071;
  int row = s >> 4;
  int c16 = s & 15;            // 8-elem slot: d = c16*8..c16*8+7
  const float* src = (arr ? Qp : Kp) + row*DD + c16*8;
  const float scale = arr ? 1.0f : 0.12751743f;   // log2(e)/sqrt(128)
  float4 f0 = ((const float4*)src)[0];
  float4 f1 = ((const float4*)src)[1];
  unsigned int wv[4];
  wv[0] = (unsigned)f2bf(f0.x*scale) | ((unsigned)f2bf(f0.y*scale) << 16);
  wv[1] = (unsigned)f2bf(f0.z*scale) | ((unsigned)f2bf(f0.w*scale) << 16);
  wv[2] = (unsigned)f2bf(f1.x*scale) | ((unsigned)f2bf(f1.y*scale) << 16);
  wv[3] = (unsigned)f2bf(f1.z*scale) | ((unsigned)f2bf(f1.w*scale) << 16);
  ushort_t* base = arr ? qst : kst;
  int tile = row >> 6, rg = (row >> 4) & 3, r15 = row & 15;
  int kk = c16 >> 2, g4 = c16 & 3;
  char* dst = (char*)base + (size_t)tile*16384 + (rg*4 + kk)*1024 + (g4*16 + r15)*16;
  ((uint4*)dst)[0] = make_uint4(wv[0],wv[1],wv[2],wv[3]);
}

// ---------------------------------------------------------------------------
// kz: per-column stats, BARRIER-FREE main loop. Wave w reads its 4 ak
// records per k-tile straight from the global K stream (L2-hot, coalesced);
// no LDS staging, no per-iter barriers -> 16 free-running waves/CU hide
// L2 latency. Q B-frags coalesced from stream into regs (as before).
// ---------------------------------------------------------------------------
__global__ __launch_bounds__(256, 4) void kz(const ushort_t* __restrict__ kst,
                                             const ushort_t* __restrict__ qst,
                                             float* __restrict__ zpart){
  __shared__ __align__(16) float zred[256];
  int wg = blockIdx.x;            // 1024
  int qs   = wg >> 3;             // 0..127 (64-q stripe)
  int kspl = wg & 7;
  int t = threadIdx.x, lane = t & 63, w = t >> 6;   // w in 0..3

  short8 qf[4][4];
  { const char* qg = (const char*)qst + (size_t)qs*16384;
    #pragma unroll
    for (int qg_=0; qg_<4; ++qg_)
      #pragma unroll
      for (int kk=0; kk<4; ++kk)
        qf[qg_][kk] = *(const short8*)(qg + ((qg_*4+kk)<<10) + lane*16);
  }

  float zac0=0.f, zac1=0.f, zac2=0.f, zac3=0.f;
  const char* kbase = (const char*)kst + (size_t)(kspl*16)*16384 + ((w*4)<<10) + lane*16;
  for (int it=0; it<16; ++it){
    short8 ak[4];
    #pragma unroll
    for (int kk=0;kk<4;kk++)
      ak[kk] = *(const short8*)(kbase + (size_t)it*16384 + (kk<<10));
    f32x4 s0={0,0,0,0}, s1={0,0,0,0}, s2={0,0,0,0}, s3={0,0,0,0};
    #pragma unroll
    for (int kk=0; kk<4; ++kk){
      s0 = __builtin_amdgcn_mfma_f32_16x16x32_bf16(ak[kk], qf[0][kk], s0, 0, 0, 0);
      s1 = __builtin_amdgcn_mfma_f32_16x16x32_bf16(ak[kk], qf[1][kk], s1, 0, 0, 0);
      s2 = __builtin_amdgcn_mfma_f32_16x16x32_bf16(ak[kk], qf[2][kk], s2, 0, 0, 0);
      s3 = __builtin_amdgcn_mfma_f32_16x16x32_bf16(ak[kk], qf[3][kk], s3, 0, 0, 0);
    }
    #pragma unroll
    for (int j=0;j<4;j++){
      zac0 += __builtin_exp2f(s0[j]);
      zac1 += __builtin_exp2f(s1[j]);
      zac2 += __builtin_exp2f(s2[j]);
      zac3 += __builtin_exp2f(s3[j]);
    }
  }
  zac0 += __shfl_xor(zac0,16); zac0 += __shfl_xor(zac0,32);
  zac1 += __shfl_xor(zac1,16); zac1 += __shfl_xor(zac1,32);
  zac2 += __shfl_xor(zac2,16); zac2 += __shfl_xor(zac2,32);
  zac3 += __shfl_xor(zac3,16); zac3 += __shfl_xor(zac3,32);
  if (lane < 16){
    zred[w*64 + 0*16 + lane] = zac0;
    zred[w*64 + 1*16 + lane] = zac1;
    zred[w*64 + 2*16 + lane] = zac2;
    zred[w*64 + 3*16 + lane] = zac3;
  }
  __syncthreads();
  if (t < 64){
    float z = zred[t] + zred[64+t] + zred[128+t] + zred[192+t];
    zpart[(size_t)kspl*SQ + qs*64 + t] = z;
  }
}

// ---------------------------------------------------------------------------
// prep_v: runs AFTER kz. Vt[q,:] = V[q,:] / Z_q, written as V stream records.
// ---------------------------------------------------------------------------
__global__ __launch_bounds__(256) void prep_v(const float* __restrict__ Vp,
                                              const float* __restrict__ zpart,
                                              ushort_t* __restrict__ vst){
  __shared__ ushort_t vl[64][132];
  int tile = blockIdx.x;    // 0..127
  int t = threadIdx.x;
  int q = t >> 2, dvb4 = (t & 3)*32;
  float z = 0.f;
  #pragma unroll
  for (int s=0;s<ZSPLIT;s++) z += zpart[(size_t)s*SQ + tile*64 + q];
  float vinv = 1.0f / z;
  const float* src = Vp + (size_t)(tile*64 + q)*DD + dvb4;
  #pragma unroll
  for (int j=0;j<8;j++){
    float4 f = ((const float4*)src)[j];
    vl[q][dvb4 + j*4 + 0] = f2bf(f.x*vinv);
    vl[q][dvb4 + j*4 + 1] = f2bf(f.y*vinv);
    vl[q][dvb4 + j*4 + 2] = f2bf(f.z*vinv);
    vl[q][dvb4 + j*4 + 3] = f2bf(f.w*vinv);
  }
  __syncthreads();
  char* obase = (char*)vst + (size_t)tile*16384;
  #pragma unroll
  for (int s2=0;s2<4;s2++){
    int sid = t*4 + s2;                 // 0..1023 = rec*64 + lane
    int rec = sid >> 6, lr = sid & 63;
    int dv = (rec & 7)*16 + (lr & 15);
    int qb = (rec >> 3)*32 + (lr >> 4)*8;
    unsigned int wv[4];
    #pragma unroll
    for (int p=0;p<4;p++){
      unsigned lo = vl[qb + p*2 + 0][dv];
      unsigned hi = vl[qb + p*2 + 1][dv];
      wv[p] = lo | (hi << 16);
    }
    ((uint4*)(obase + rec*1024 + lr*16))[0] = make_uint4(wv[0],wv[1],wv[2],wv[3]);
  }
}

// ---------------------------------------------------------------------------
// ko: r13's R=4 math, barriers HALVED: two q-tiles staged per round.
// Grid = 32 k-supertiles (256 rows) x 8 qsp = 256 WGs x 512 thr (1/CU).
// LDS = 2 x 64KB (each half = {Q(2s) 16K | V(2s) 16K | Q(2s+1) 16K |
// V(2s+1) 16K}); 8 super-iters, 1 barrier each. Wave (kg,qh): 64 k-rows
// (kf[4][4] from global K stream) vs its 32-q half; fragment algebra
// byte-identical to r13. Deterministic epilogue (qh-pair LDS reduce ->
// 8 atomics/element, XCD-local).
// ---------------------------------------------------------------------------
__global__ __launch_bounds__(512, 1) void ko(const ushort_t* __restrict__ kst,
                                             const ushort_t* __restrict__ qst,
                                             const ushort_t* __restrict__ vst,
                                             float* __restrict__ out){
  __shared__ __align__(16) char smem[131072];  // dbuf 2 x 64KB (2 q-tiles each)
  int wg = blockIdx.x;            // 256
  int kt2 = wg & 31;              // 0..31 (256 k-rows); xcd = kt2%8
  int qsp = wg >> 5;              // 0..7  (16 q-tiles of 64)
  int t = threadIdx.x, lane = t & 63, w = t >> 6;   // w in 0..7
  int kg = w & 3, qh = w >> 2;
  int r15 = lane & 15, g4 = lane >> 4;

  // kf[kb][kk]: wave's 64 k-rows, one-time coalesced global reads
  short8 kf[4][4];
  { const char* kb = (const char*)kst + (size_t)(kt2*4 + kg)*16384;
    #pragma unroll
    for (int b=0;b<4;b++)
      #pragma unroll
      for (int kk=0;kk<4;kk++)
        kf[b][kk] = *(const short8*)(kb + ((b*4+kk)<<10) + lane*16);
  }
  // stage pair 0 (q-tiles 0,1) into buf0
  { const char* qg = (const char*)qst + (size_t)(qsp*16)*16384;
    const char* vg = (const char*)vst + (size_t)(qsp*16)*16384;
    #pragma unroll
    for (int j=0;j<2;j++)
      #pragma unroll
      for (int i=0;i<2;i++){
        gld16(qg + j*16384 + (t + i*512)*16, smem + j*32768 + (t + i*512)*16);
        gld16(vg + j*16384 + (t + i*512)*16, smem + j*32768 + 16384 + (t + i*512)*16);
      }
  }

  f32x4 zero = {0.f,0.f,0.f,0.f};
  f32x4 acc[4][8];
  #pragma unroll
  for (int b=0;b<4;b++)
    #pragma unroll
    for (int i=0;i<8;i++) acc[b][i] = zero;

  for (int sit=0; sit<8; ++sit){
    __syncthreads();                 // buf(sit) DMA drained; buf(sit^1) free
    const char* Buf = smem + (sit&1)*65536;
    // prefetch next pair into other buffer (drained at next barrier)
    if (sit+1 < 8){
      const char* qg = (const char*)qst + (size_t)(qsp*16 + (sit+1)*2)*16384;
      const char* vg = (const char*)vst + (size_t)(qsp*16 + (sit+1)*2)*16384;
      char* dst = smem + ((sit+1)&1)*65536;
      #pragma unroll
      for (int j=0;j<2;j++)
        #pragma unroll
        for (int i=0;i<2;i++){
          gld16(qg + j*16384 + (t + i*512)*16, dst + j*32768 + (t + i*512)*16);
          gld16(vg + j*16384 + (t + i*512)*16, dst + j*32768 + 16384 + (t + i*512)*16);
        }
    }
    #pragma unroll
    for (int j=0;j<2;j++){
      const char* Qb = Buf + j*32768;
      const char* Vb = Qb + 16384;
      // ---- G1: S^T for 4 k-blocks x wave's 32-q half ----
      unsigned pw[4][4];               // [kb][word]
      #pragma unroll
      for (int blk=0; blk<2; ++blk){
        f32x4 s[4];
        #pragma unroll
        for (int b=0;b<4;b++) s[b] = zero;
        #pragma unroll
        for (int kk=0; kk<4; ++kk){
          short8 aq = *(const short8*)(Qb + (((qh*2+blk)*4+kk)<<10) + lane*16);
          #pragma unroll
          for (int b=0;b<4;b++)
            s[b] = __builtin_amdgcn_mfma_f32_16x16x32_bf16(aq, kf[b][kk], s[b], 0, 0, 0);
        }
        #pragma unroll
        for (int b=0;b<4;b++){
          float p0 = __builtin_exp2f(s[b][0]);
          float p1 = __builtin_exp2f(s[b][1]);
          float p2 = __builtin_exp2f(s[b][2]);
          float p3 = __builtin_exp2f(s[b][3]);
          unsigned wa, wb;
          asm("v_cvt_pk_bf16_f32 %0, %1, %2" : "=v"(wa) : "v"(p0), "v"(p1));
          asm("v_cvt_pk_bf16_f32 %0, %1, %2" : "=v"(wb) : "v"(p2), "v"(p3));
          pw[b][blk*2+0] = wa;
          pw[b][blk*2+1] = wb;
        }
      }
      short8 af[4];
      #pragma unroll
      for (int b=0;b<4;b++){
        asm("v_permlane32_swap_b32 %0, %1" : "+v"(pw[b][0]), "+v"(pw[b][2]));
        asm("v_permlane32_swap_b32 %0, %1" : "+v"(pw[b][1]), "+v"(pw[b][3]));
        asm("v_permlane16_swap_b32 %0, %1" : "+v"(pw[b][0]), "+v"(pw[b][2]));
        asm("v_permlane16_swap_b32 %0, %1" : "+v"(pw[b][1]), "+v"(pw[b][3]));
        uint4v fw = { pw[b][0], pw[b][1], pw[b][2], pw[b][3] };
        af[b] = __builtin_bit_cast(short8, fw);
      }
      // ---- PV: each V record feeds all 4 k-blocks ----
      __builtin_amdgcn_s_setprio(1);
      #pragma unroll
      for (int dvb=0; dvb<8; ++dvb){
        short8 bv = *(const short8*)(Vb + ((qh*8+dvb)<<10) + lane*16);
        #pragma unroll
        for (int b=0;b<4;b++)
          acc[b][dvb] = __builtin_amdgcn_mfma_f32_16x16x32_bf16(af[b], bv, acc[b][dvb], 0, 0, 0);
      }
      __builtin_amdgcn_s_setprio(0);
    }
  }
  // ---- epilogue: deterministic qh-pair reduce via LDS (2 x 64KB passes),
  //      then 8 atomics/element from qh=0 waves (XCD-local) ----
  f32x4* red = (f32x4*)smem;         // [b2*8+dvb][kg*64+lane]
  #pragma unroll
  for (int pass=0; pass<2; ++pass){
    __syncthreads();                 // buffers/prev-pass reads complete
    if (qh == 1){
      #pragma unroll
      for (int b2=0;b2<2;b2++)
        #pragma unroll
        for (int dvb=0; dvb<8; ++dvb)
          red[((b2*8 + dvb)<<8) + kg*64 + lane] = acc[pass*2+b2][dvb];
    }
    __syncthreads();
    if (qh == 0){
      #pragma unroll
      for (int b2=0;b2<2;b2++)
        #pragma unroll
        for (int dvb=0; dvb<8; ++dvb){
          f32x4 o = red[((b2*8 + dvb)<<8) + kg*64 + lane];
          f32x4 a = acc[pass*2+b2][dvb];
          #pragma unroll
          for (int j=0;j<4;j++){
            int k  = kt2*256 + kg*64 + (pass*2+b2)*16 + g4*4 + j;
            int dv = dvb*16 + r15;
            atomicAdd(out + (size_t)k*DD + dv, a[j] + o[j]);
          }
        }
    }
  }
}

extern "C" void kernel_launch(void* const* d_in, const int* in_sizes, int n_in,
                              void* d_out, int out_size, void* d_ws, size_t ws_size,
                              hipStream_t stream) {
  const float* Kp = (const float*)d_in[0];
  const float* Qp = (const float*)d_in[1];
  const float* Vp = (const float*)d_in[2];
  float* out = (float*)d_out;
  char* ws = (char*)d_ws;
  ushort_t* kst  = (ushort_t*)ws;
  ushort_t* qst  = (ushort_t*)(ws + ((size_t)2<<20));
  ushort_t* vst  = (ushort_t*)(ws + ((size_t)4<<20));
  float* zpart   = (float*)(ws + ((size_t)6<<20));

  hipMemsetAsync(d_out, 0, (size_t)SK*DD*sizeof(float), stream);
  prep_kq<<<dim3(1024), dim3(256), 0, stream>>>(Kp, Qp, kst, qst);
  kz     <<<dim3(1024), dim3(256), 0, stream>>>(kst, qst, zpart);
  prep_v <<<dim3(128),  dim3(256), 0, stream>>>(Vp, zpart, vst);
  ko     <<<dim3(256),  dim3(512), 0, stream>>>(kst, qst, vst, out);
}

// Round 15
// 85.743 us; speedup vs baseline: 1.6908x; 1.1812x over previous
//
#include <hip/hip_runtime.h>

#define SK 8192
#define SQ 8192
#define DD 128
#define ZSPLIT 8

typedef __attribute__((ext_vector_type(8))) short short8;
typedef __attribute__((ext_vector_type(4))) float f32x4;
typedef __attribute__((ext_vector_type(4))) unsigned uint4v;
typedef unsigned short ushort_t;

// round-to-nearest-even f32 -> bf16
__device__ __forceinline__ unsigned short f2bf(float x){
  unsigned int u = __float_as_uint(x);
  u += 0x7FFFu + ((u >> 16) & 1u);
  return (unsigned short)(u >> 16);
}

// async global->LDS DMA, 16B/lane. LDS dest = uniform base + lane*16.
__device__ __forceinline__ void gld16(const void* g, void* l){
  __builtin_amdgcn_global_load_lds(
      (const __attribute__((address_space(1))) unsigned int*)g,
      (__attribute__((address_space(3))) unsigned int*)l, 16, 0, 0);
}

// ---------------------------------------------------------------------------
// STREAM LAYOUTS (fragment-record form; all reads are coalesced 1KB records)
// K/Q stream: per 64-row tile, 16 records of 1KB; rec = rg*4 + kk.
//   Lane l, byte pair j: element M[tile*64 + rg*16 + (l&15)][kk*32 + (l>>4)*8 + j]
// V stream: per 64-q tile, 16 records; rec = qc*8 + dvb. Lane l:
//   element V^T[dvb*16 + (l&15)][qc*32 + (l>>4)*8 + j]  (V^T pre-scaled 1/Z)
// ---------------------------------------------------------------------------

// prep_kq: cast K (pre-scaled by log2(e)/sqrt(128)) and Q to bf16 streams.
__global__ __launch_bounds__(256) void prep_kq(const float* __restrict__ Kp,
                                               const float* __restrict__ Qp,
                                               ushort_t* __restrict__ kst,
                                               ushort_t* __restrict__ qst){
  int g = blockIdx.x*256 + threadIdx.x;
  int arr = g >> 17;
  int s   = g & 131071;
  int row = s >> 4;
  int c16 = s & 15;            // 8-elem slot: d = c16*8..c16*8+7
  const float* src = (arr ? Qp : Kp) + row*DD + c16*8;
  const float scale = arr ? 1.0f : 0.12751743f;   // log2(e)/sqrt(128)
  float4 f0 = ((const float4*)src)[0];
  float4 f1 = ((const float4*)src)[1];
  unsigned int wv[4];
  wv[0] = (unsigned)f2bf(f0.x*scale) | ((unsigned)f2bf(f0.y*scale) << 16);
  wv[1] = (unsigned)f2bf(f0.z*scale) | ((unsigned)f2bf(f0.w*scale) << 16);
  wv[2] = (unsigned)f2bf(f1.x*scale) | ((unsigned)f2bf(f1.y*scale) << 16);
  wv[3] = (unsigned)f2bf(f1.z*scale) | ((unsigned)f2bf(f1.w*scale) << 16);
  ushort_t* base = arr ? qst : kst;
  int tile = row >> 6, rg = (row >> 4) & 3, r15 = row & 15;
  int kk = c16 >> 2, g4 = c16 & 3;
  char* dst = (char*)base + (size_t)tile*16384 + (rg*4 + kk)*1024 + (g4*16 + r15)*16;
  ((uint4*)dst)[0] = make_uint4(wv[0],wv[1],wv[2],wv[3]);
}

// ---------------------------------------------------------------------------
// kz: per-column stats, BARRIER-FREE main loop (r14, passing).
// ---------------------------------------------------------------------------
__global__ __launch_bounds__(256, 4) void kz(const ushort_t* __restrict__ kst,
                                             const ushort_t* __restrict__ qst,
                                             float* __restrict__ zpart){
  __shared__ __align__(16) float zred[256];
  int wg = blockIdx.x;            // 1024
  int qs   = wg >> 3;             // 0..127 (64-q stripe)
  int kspl = wg & 7;
  int t = threadIdx.x, lane = t & 63, w = t >> 6;   // w in 0..3

  short8 qf[4][4];
  { const char* qg = (const char*)qst + (size_t)qs*16384;
    #pragma unroll
    for (int qg_=0; qg_<4; ++qg_)
      #pragma unroll
      for (int kk=0; kk<4; ++kk)
        qf[qg_][kk] = *(const short8*)(qg + ((qg_*4+kk)<<10) + lane*16);
  }

  float zac0=0.f, zac1=0.f, zac2=0.f, zac3=0.f;
  const char* kbase = (const char*)kst + (size_t)(kspl*16)*16384 + ((w*4)<<10) + lane*16;
  for (int it=0; it<16; ++it){
    short8 ak[4];
    #pragma unroll
    for (int kk=0;kk<4;kk++)
      ak[kk] = *(const short8*)(kbase + (size_t)it*16384 + (kk<<10));
    f32x4 s0={0,0,0,0}, s1={0,0,0,0}, s2={0,0,0,0}, s3={0,0,0,0};
    #pragma unroll
    for (int kk=0; kk<4; ++kk){
      s0 = __builtin_amdgcn_mfma_f32_16x16x32_bf16(ak[kk], qf[0][kk], s0, 0, 0, 0);
      s1 = __builtin_amdgcn_mfma_f32_16x16x32_bf16(ak[kk], qf[1][kk], s1, 0, 0, 0);
      s2 = __builtin_amdgcn_mfma_f32_16x16x32_bf16(ak[kk], qf[2][kk], s2, 0, 0, 0);
      s3 = __builtin_amdgcn_mfma_f32_16x16x32_bf16(ak[kk], qf[3][kk], s3, 0, 0, 0);
    }
    #pragma unroll
    for (int j=0;j<4;j++){
      zac0 += __builtin_exp2f(s0[j]);
      zac1 += __builtin_exp2f(s1[j]);
      zac2 += __builtin_exp2f(s2[j]);
      zac3 += __builtin_exp2f(s3[j]);
    }
  }
  zac0 += __shfl_xor(zac0,16); zac0 += __shfl_xor(zac0,32);
  zac1 += __shfl_xor(zac1,16); zac1 += __shfl_xor(zac1,32);
  zac2 += __shfl_xor(zac2,16); zac2 += __shfl_xor(zac2,32);
  zac3 += __shfl_xor(zac3,16); zac3 += __shfl_xor(zac3,32);
  if (lane < 16){
    zred[w*64 + 0*16 + lane] = zac0;
    zred[w*64 + 1*16 + lane] = zac1;
    zred[w*64 + 2*16 + lane] = zac2;
    zred[w*64 + 3*16 + lane] = zac3;
  }
  __syncthreads();
  if (t < 64){
    float z = zred[t] + zred[64+t] + zred[128+t] + zred[192+t];
    zpart[(size_t)kspl*SQ + qs*64 + t] = z;
  }
}

// ---------------------------------------------------------------------------
// prep_v: runs AFTER kz. Vt[q,:] = V[q,:] / Z_q, written as V stream records.
// ---------------------------------------------------------------------------
__global__ __launch_bounds__(256) void prep_v(const float* __restrict__ Vp,
                                              const float* __restrict__ zpart,
                                              ushort_t* __restrict__ vst){
  __shared__ ushort_t vl[64][132];
  int tile = blockIdx.x;    // 0..127
  int t = threadIdx.x;
  int q = t >> 2, dvb4 = (t & 3)*32;
  float z = 0.f;
  #pragma unroll
  for (int s=0;s<ZSPLIT;s++) z += zpart[(size_t)s*SQ + tile*64 + q];
  float vinv = 1.0f / z;
  const float* src = Vp + (size_t)(tile*64 + q)*DD + dvb4;
  #pragma unroll
  for (int j=0;j<8;j++){
    float4 f = ((const float4*)src)[j];
    vl[q][dvb4 + j*4 + 0] = f2bf(f.x*vinv);
    vl[q][dvb4 + j*4 + 1] = f2bf(f.y*vinv);
    vl[q][dvb4 + j*4 + 2] = f2bf(f.z*vinv);
    vl[q][dvb4 + j*4 + 3] = f2bf(f.w*vinv);
  }
  __syncthreads();
  char* obase = (char*)vst + (size_t)tile*16384;
  #pragma unroll
  for (int s2=0;s2<4;s2++){
    int sid = t*4 + s2;                 // 0..1023 = rec*64 + lane
    int rec = sid >> 6, lr = sid & 63;
    int dv = (rec & 7)*16 + (lr & 15);
    int qb = (rec >> 3)*32 + (lr >> 4)*8;
    unsigned int wv[4];
    #pragma unroll
    for (int p=0;p<4;p++){
      unsigned lo = vl[qb + p*2 + 0][dv];
      unsigned hi = vl[qb + p*2 + 1][dv];
      wv[p] = lo | (hi << 16);
    }
    ((uint4*)(obase + rec*1024 + lr*16))[0] = make_uint4(wv[0],wv[1],wv[2],wv[3]);
  }
}

// ---------------------------------------------------------------------------
// ko: r14 compute, NEW epilogue: if `part` != null, each WG plain-stores its
// deterministically qh-reduced 256k x 128dv tile into partial slice [qsp]
// (no atomics -> no memory-side RMW floor). Else r14 atomic fallback.
// ---------------------------------------------------------------------------
__global__ __launch_bounds__(512, 1) void ko(const ushort_t* __restrict__ kst,
                                             const ushort_t* __restrict__ qst,
                                             const ushort_t* __restrict__ vst,
                                             float* __restrict__ part,
                                             float* __restrict__ out){
  __shared__ __align__(16) char smem[131072];  // dbuf 2 x 64KB (2 q-tiles each)
  int wg = blockIdx.x;            // 256
  int kt2 = wg & 31;              // 0..31 (256 k-rows); xcd = kt2%8
  int qsp = wg >> 5;              // 0..7  (16 q-tiles of 64)
  int t = threadIdx.x, lane = t & 63, w = t >> 6;   // w in 0..7
  int kg = w & 3, qh = w >> 2;
  int r15 = lane & 15, g4 = lane >> 4;

  // kf[kb][kk]: wave's 64 k-rows, one-time coalesced global reads
  short8 kf[4][4];
  { const char* kb = (const char*)kst + (size_t)(kt2*4 + kg)*16384;
    #pragma unroll
    for (int b=0;b<4;b++)
      #pragma unroll
      for (int kk=0;kk<4;kk++)
        kf[b][kk] = *(const short8*)(kb + ((b*4+kk)<<10) + lane*16);
  }
  // stage pair 0 (q-tiles 0,1) into buf0
  { const char* qg = (const char*)qst + (size_t)(qsp*16)*16384;
    const char* vg = (const char*)vst + (size_t)(qsp*16)*16384;
    #pragma unroll
    for (int j=0;j<2;j++)
      #pragma unroll
      for (int i=0;i<2;i++){
        gld16(qg + j*16384 + (t + i*512)*16, smem + j*32768 + (t + i*512)*16);
        gld16(vg + j*16384 + (t + i*512)*16, smem + j*32768 + 16384 + (t + i*512)*16);
      }
  }

  f32x4 zero = {0.f,0.f,0.f,0.f};
  f32x4 acc[4][8];
  #pragma unroll
  for (int b=0;b<4;b++)
    #pragma unroll
    for (int i=0;i<8;i++) acc[b][i] = zero;

  for (int sit=0; sit<8; ++sit){
    __syncthreads();                 // buf(sit) DMA drained; buf(sit^1) free
    const char* Buf = smem + (sit&1)*65536;
    if (sit+1 < 8){
      const char* qg = (const char*)qst + (size_t)(qsp*16 + (sit+1)*2)*16384;
      const char* vg = (const char*)vst + (size_t)(qsp*16 + (sit+1)*2)*16384;
      char* dst = smem + ((sit+1)&1)*65536;
      #pragma unroll
      for (int j=0;j<2;j++)
        #pragma unroll
        for (int i=0;i<2;i++){
          gld16(qg + j*16384 + (t + i*512)*16, dst + j*32768 + (t + i*512)*16);
          gld16(vg + j*16384 + (t + i*512)*16, dst + j*32768 + 16384 + (t + i*512)*16);
        }
    }
    #pragma unroll
    for (int j=0;j<2;j++){
      const char* Qb = Buf + j*32768;
      const char* Vb = Qb + 16384;
      // ---- G1: S^T for 4 k-blocks x wave's 32-q half ----
      unsigned pw[4][4];               // [kb][word]
      #pragma unroll
      for (int blk=0; blk<2; ++blk){
        f32x4 s[4];
        #pragma unroll
        for (int b=0;b<4;b++) s[b] = zero;
        #pragma unroll
        for (int kk=0; kk<4; ++kk){
          short8 aq = *(const short8*)(Qb + (((qh*2+blk)*4+kk)<<10) + lane*16);
          #pragma unroll
          for (int b=0;b<4;b++)
            s[b] = __builtin_amdgcn_mfma_f32_16x16x32_bf16(aq, kf[b][kk], s[b], 0, 0, 0);
        }
        #pragma unroll
        for (int b=0;b<4;b++){
          float p0 = __builtin_exp2f(s[b][0]);
          float p1 = __builtin_exp2f(s[b][1]);
          float p2 = __builtin_exp2f(s[b][2]);
          float p3 = __builtin_exp2f(s[b][3]);
          unsigned wa, wb;
          asm("v_cvt_pk_bf16_f32 %0, %1, %2" : "=v"(wa) : "v"(p0), "v"(p1));
          asm("v_cvt_pk_bf16_f32 %0, %1, %2" : "=v"(wb) : "v"(p2), "v"(p3));
          pw[b][blk*2+0] = wa;
          pw[b][blk*2+1] = wb;
        }
      }
      short8 af[4];
      #pragma unroll
      for (int b=0;b<4;b++){
        asm("v_permlane32_swap_b32 %0, %1" : "+v"(pw[b][0]), "+v"(pw[b][2]));
        asm("v_permlane32_swap_b32 %0, %1" : "+v"(pw[b][1]), "+v"(pw[b][3]));
        asm("v_permlane16_swap_b32 %0, %1" : "+v"(pw[b][0]), "+v"(pw[b][2]));
        asm("v_permlane16_swap_b32 %0, %1" : "+v"(pw[b][1]), "+v"(pw[b][3]));
        uint4v fw = { pw[b][0], pw[b][1], pw[b][2], pw[b][3] };
        af[b] = __builtin_bit_cast(short8, fw);
      }
      // ---- PV: each V record feeds all 4 k-blocks ----
      __builtin_amdgcn_s_setprio(1);
      #pragma unroll
      for (int dvb=0; dvb<8; ++dvb){
        short8 bv = *(const short8*)(Vb + ((qh*8+dvb)<<10) + lane*16);
        #pragma unroll
        for (int b=0;b<4;b++)
          acc[b][dvb] = __builtin_amdgcn_mfma_f32_16x16x32_bf16(af[b], bv, acc[b][dvb], 0, 0, 0);
      }
      __builtin_amdgcn_s_setprio(0);
    }
  }
  // ---- epilogue: deterministic qh-pair reduce via LDS (2 x 64KB passes),
  //      then plain stores into partial slice [qsp] (or atomic fallback) ----
  f32x4* red = (f32x4*)smem;         // [b2*8+dvb][kg*64+lane]
  float* ps = part ? (part + (size_t)qsp*SK*DD) : 0;
  #pragma unroll
  for (int pass=0; pass<2; ++pass){
    __syncthreads();                 // buffers/prev-pass reads complete
    if (qh == 1){
      #pragma unroll
      for (int b2=0;b2<2;b2++)
        #pragma unroll
        for (int dvb=0; dvb<8; ++dvb)
          red[((b2*8 + dvb)<<8) + kg*64 + lane] = acc[pass*2+b2][dvb];
    }
    __syncthreads();
    if (qh == 0){
      #pragma unroll
      for (int b2=0;b2<2;b2++)
        #pragma unroll
        for (int dvb=0; dvb<8; ++dvb){
          f32x4 o = red[((b2*8 + dvb)<<8) + kg*64 + lane];
          f32x4 a = acc[pass*2+b2][dvb];
          #pragma unroll
          for (int j=0;j<4;j++){
            int k  = kt2*256 + kg*64 + (pass*2+b2)*16 + g4*4 + j;
            int dv = dvb*16 + r15;
            if (ps) ps[(size_t)k*DD + dv] = a[j] + o[j];
            else    atomicAdd(out + (size_t)k*DD + dv, a[j] + o[j]);
          }
        }
    }
  }
}

// ---------------------------------------------------------------------------
// kred: out = sum of 8 partial slices, fixed order (deterministic).
// 1024 blocks x 256 thr, float4 per thread: reads 33.6MB, writes 4MB.
// ---------------------------------------------------------------------------
__global__ __launch_bounds__(256) void kred(const float* __restrict__ part,
                                            float* __restrict__ out){
  int i = blockIdx.x*256 + threadIdx.x;          // 0..262143
  const float4* p = (const float4*)part;
  float4 a = p[i];
  #pragma unroll
  for (int s=1;s<8;s++){
    float4 b = p[(size_t)s*262144 + i];
    a.x += b.x; a.y += b.y; a.z += b.z; a.w += b.w;
  }
  ((float4*)out)[i] = a;
}

extern "C" void kernel_launch(void* const* d_in, const int* in_sizes, int n_in,
                              void* d_out, int out_size, void* d_ws, size_t ws_size,
                              hipStream_t stream) {
  const float* Kp = (const float*)d_in[0];
  const float* Qp = (const float*)d_in[1];
  const float* Vp = (const float*)d_in[2];
  float* out = (float*)d_out;
  char* ws = (char*)d_ws;
  ushort_t* kst  = (ushort_t*)ws;
  ushort_t* qst  = (ushort_t*)(ws + ((size_t)2<<20));
  ushort_t* vst  = (ushort_t*)(ws + ((size_t)4<<20));
  float* zpart   = (float*)(ws + ((size_t)6<<20));
  // partials: 8 slices x 4MB at ws+8MB (needs ws_size >= 40MB)
  bool use_part = ws_size >= ((size_t)40<<20);
  float* part = use_part ? (float*)(ws + ((size_t)8<<20)) : (float*)0;

  prep_kq<<<dim3(1024), dim3(256), 0, stream>>>(Kp, Qp, kst, qst);
  kz     <<<dim3(1024), dim3(256), 0, stream>>>(kst, qst, zpart);
  prep_v <<<dim3(128),  dim3(256), 0, stream>>>(Vp, zpart, vst);
  if (use_part){
    ko   <<<dim3(256),  dim3(512), 0, stream>>>(kst, qst, vst, part, out);
    kred <<<dim3(1024), dim3(256), 0, stream>>>(part, out);
  } else {
    hipMemsetAsync(d_out, 0, (size_t)SK*DD*sizeof(float), stream);
    ko   <<<dim3(256),  dim3(512), 0, stream>>>(kst, qst, vst, (float*)0, out);
  }
}